// Round 6
// baseline (57.345 us; speedup 1.0000x reference)
//
#include <hip/hip_runtime.h>
#include <math.h>

#define B_ 4
#define T_ 512
#define D_ 2048
#define H_ 1024
#define E_ 2
#define NBLK 512
#define NTHR 256

#define LD4(p) (*reinterpret_cast<const float4*>(p))

__device__ __forceinline__ float waveReduceSum(float v) {
    #pragma unroll
    for (int o = 32; o > 0; o >>= 1) v += __shfl_down(v, o, 64);
    return v;
}

// Relaxed device-scope (sc1) point ops. Lessons encoded here:
//  R2: NO __threadfence / release-acquire (emits buffer_wbl2/buffer_inv, ~38us).
//  R4: NO spinning on a line that is being RMW'd (ownership ping-pong, ~20us/barrier).
//  R5: NO same-line RMW arrivals (512 serialized fetch_adds ~ +7us).
__device__ __forceinline__ void agentStoreF(float* p, float v) {
    __hip_atomic_store(p, v, __ATOMIC_RELAXED, __HIP_MEMORY_SCOPE_AGENT);
}
__device__ __forceinline__ float agentLoadF(const float* p) {
    return __hip_atomic_load(p, __ATOMIC_RELAXED, __HIP_MEMORY_SCOPE_AGENT);
}
__device__ __forceinline__ void agentStoreI(int* p, int v) {
    __hip_atomic_store(p, v, __ATOMIC_RELAXED, __HIP_MEMORY_SCOPE_AGENT);
}
__device__ __forceinline__ int agentLoadI(const int* p) {
    return __hip_atomic_load(p, __ATOMIC_RELAXED, __HIP_MEMORY_SCOPE_AGENT);
}

// ctrl layout (ints): [0..511] arrive0 | [512..1023] arrive1 | [1024..1535] arrive2
// | [1536 + bar*256 + copy*32] release flags (8 copies per barrier, 128B apart).
// Store-array arrivals (no RMW); one collector wave; replicated release lines.
__device__ __forceinline__ void gridBarrier(int bar, int* ctrl, int bid) {
    int* arrive  = ctrl + bar * NBLK;
    int* release = ctrl + 3 * NBLK + bar * 256;
    __syncthreads();                            // per-wave vmcnt(0): phase stores acked
    if (threadIdx.x == 0) agentStoreI(&arrive[bid], 1);
    asm volatile("" ::: "memory");
    if (bid == 0) {
        if (threadIdx.x < 64) {                 // wave 0 collects
            for (;;) {
                int acc = 1;
                #pragma unroll
                for (int k = 0; k < NBLK / 64; ++k)
                    acc &= agentLoadI(&arrive[threadIdx.x + k * 64]);
                if (__all(acc == 1)) break;
                __builtin_amdgcn_s_sleep(4);
            }
            if (threadIdx.x < 8) agentStoreI(&release[threadIdx.x * 32], 1);
        }
    } else {
        if (threadIdx.x == 0) {
            while (agentLoadI(&release[(bid & 7) * 32]) == 0)
                __builtin_amdgcn_s_sleep(16);   // read-only poll, 64 pollers/line
        }
    }
    asm volatile("" ::: "memory");
    __syncthreads();
}

__global__ __launch_bounds__(NTHR) void k_moe(
        const float* __restrict__ x,  const float* __restrict__ Wg,
        const float* __restrict__ W1, const float* __restrict__ b1,
        const float* __restrict__ W2, const float* __restrict__ b2,
        float* __restrict__ out, float* __restrict__ w2s, float* __restrict__ v,
        float* __restrict__ c, float* __restrict__ s, int* __restrict__ ctrl) {
    const int bid  = blockIdx.x;
    const int lane = threadIdx.x & 63;
    const int wid  = threadIdx.x >> 6;
    const int gw   = bid * 4 + wid;             // global wave id 0..2047

    // ---- Phase A: w2s[gw] = sum_d W2[gw,d] (one wave per row) ----
    {
        const float* p = W2 + (size_t)gw * D_;
        float acc = 0.f;
        #pragma unroll
        for (int k = 0; k < D_ / 256; ++k) {    // 8 float4 per lane
            float4 a = LD4(p + (lane + k * 64) * 4);
            acc += (a.x + a.y) + (a.z + a.w);
        }
        acc = waveReduceSum(acc);
        if (lane == 0) agentStoreF(&w2s[gw], acc);
    }
    gridBarrier(0, ctrl, bid);

    // ---- Phase B: v[row] = sum_h W1[row,h]*w2s[e,h] (2 rows per wave) ----
    {
        #pragma unroll
        for (int r = 0; r < 2; ++r) {
            int row = 2 * gw + r;               // 0..4095 = e*D_ + d
            int e   = row >> 11;
            const float* p = W1 + (size_t)row * H_;
            const float* w = w2s + e * H_;      // plain reads: never dirty in any L2
            float acc = 0.f;
            #pragma unroll
            for (int k = 0; k < H_ / 256; ++k) {
                float4 a = LD4(p + (lane + k * 64) * 4);
                float4 b = LD4(w + (lane + k * 64) * 4);
                acc += a.x * b.x + a.y * b.y + a.z * b.z + a.w * b.w;
            }
            acc = waveReduceSum(acc);
            if (lane == 0) agentStoreF(&v[row], acc);
        }
        if (bid == NBLK - 1 && wid < 2) {       // wave e computes c[e]
            int e = wid;
            float acc = 0.f;
            for (int i = lane; i < H_; i += 64) acc += b1[e * H_ + i] * w2s[e * H_ + i];
            for (int i = lane; i < D_; i += 64) acc += b2[e * D_ + i];
            acc = waveReduceSum(acc);
            if (lane == 0) agentStoreF(&c[e], acc);
        }
    }
    gridBarrier(1, ctrl, bid);

    // ---- Phase C: one wave per token; gates + both expert dots, one x pass ----
    {
        float cc0 = c[0], cc1 = c[1];
        const float* xp = x + (size_t)gw * D_;
        float g0 = 0.f, g1 = 0.f, d0 = 0.f, d1 = 0.f;
        #pragma unroll
        for (int k = 0; k < D_ / 256; ++k) {
            int i = (lane + k * 64) * 4;
            float4 xv = LD4(xp + i);
            float4 v0 = LD4(v + i);
            float4 v1 = LD4(v + D_ + i);
            float4 wa = LD4(Wg + 2 * i);        // Wg[d=i..i+1, e=0..1]
            float4 wb = LD4(Wg + 2 * i + 4);
            g0 += xv.x * wa.x + xv.y * wa.z + xv.z * wb.x + xv.w * wb.z;
            g1 += xv.x * wa.y + xv.y * wa.w + xv.z * wb.y + xv.w * wb.w;
            d0 += xv.x * v0.x + xv.y * v0.y + xv.z * v0.z + xv.w * v0.w;
            d1 += xv.x * v1.x + xv.y * v1.y + xv.z * v1.z + xv.w * v1.w;
        }
        #pragma unroll
        for (int o = 32; o > 0; o >>= 1) {
            g0 += __shfl_down(g0, o, 64);
            g1 += __shfl_down(g1, o, 64);
            d0 += __shfl_down(d0, o, 64);
            d1 += __shfl_down(d1, o, 64);
        }
        if (lane == 0) {
            int e = (g1 > g0) ? 1 : 0;          // argmax, first index on tie
            float m  = fmaxf(g0, g1);
            float p0 = expf(g0 - m), p1 = expf(g1 - m);
            float gate = ((e == 0) ? p0 : p1) / (p0 + p1);
            float dot  = (e == 0) ? d0 : d1;
            agentStoreF(&s[gw], gate * (dot + ((e == 0) ? cc0 : cc1)));
        }
    }

    // ---- Tail: store-array arrivals; block 0 collects, then does log_softmax ----
    __syncthreads();                            // drains s stores
    if (threadIdx.x == 0) agentStoreI(&ctrl[2 * NBLK + bid], 1);
    if (bid != 0) return;                       // no spinning, no release needed
    asm volatile("" ::: "memory");
    if (threadIdx.x < 64) {                     // wave 0 collects arrive2
        int* arrive2 = ctrl + 2 * NBLK;
        for (;;) {
            int acc = 1;
            #pragma unroll
            for (int k = 0; k < NBLK / 64; ++k)
                acc &= agentLoadI(&arrive2[threadIdx.x + k * 64]);
            if (__all(acc == 1)) break;
            __builtin_amdgcn_s_sleep(4);
        }
    }
    asm volatile("" ::: "memory");
    __syncthreads();

    int b = wid;                                // wave -> batch (4 waves, 4 batches)
    const float* sb = s + b * T_;
    float vals[T_ / 64];
    float m = -INFINITY;
    #pragma unroll
    for (int k = 0; k < T_ / 64; ++k) {
        vals[k] = agentLoadF(&sb[lane + k * 64]);
        m = fmaxf(m, vals[k]);
    }
    #pragma unroll
    for (int o = 1; o < 64; o <<= 1) m = fmaxf(m, __shfl_xor(m, o, 64));
    float sum = 0.f;
    #pragma unroll
    for (int k = 0; k < T_ / 64; ++k) sum += expf(vals[k] - m);
    #pragma unroll
    for (int o = 1; o < 64; o <<= 1) sum += __shfl_xor(sum, o, 64);
    float lse = m + logf(sum);
    #pragma unroll
    for (int k = 0; k < T_ / 64; ++k) out[b * T_ + lane + k * 64] = vals[k] - lse;
}

extern "C" void kernel_launch(void* const* d_in, const int* in_sizes, int n_in,
                              void* d_out, int out_size, void* d_ws, size_t ws_size,
                              hipStream_t stream) {
    (void)in_sizes; (void)n_in; (void)out_size; (void)ws_size;
    const float* x  = (const float*)d_in[0];
    const float* Wg = (const float*)d_in[1];
    const float* W1 = (const float*)d_in[2];
    const float* b1 = (const float*)d_in[3];
    const float* W2 = (const float*)d_in[4];
    const float* b2 = (const float*)d_in[5];
    float* out = (float*)d_out;

    float* ws   = (float*)d_ws;
    float* w2s  = ws;                    // [E,H]  2048 floats
    float* v    = ws + 2048;             // [E,D]  4096 floats
    float* c    = ws + 6144;             // [E]    2 floats
    float* s    = ws + 6160;             // [B,T]  2048 floats
    int*   ctrl = (int*)(ws + 8208);     // 2048 ints: arrivals + release copies

    hipMemsetAsync((void*)ctrl, 0, 2048 * sizeof(int), stream);

    void* args[] = {(void*)&x, (void*)&Wg, (void*)&W1, (void*)&b1, (void*)&W2,
                    (void*)&b2, (void*)&out, (void*)&w2s, (void*)&v, (void*)&c,
                    (void*)&s, (void*)&ctrl};
    hipLaunchCooperativeKernel((const void*)k_moe, dim3(NBLK), dim3(NTHR),
                               args, 0, stream);
}

// Round 7
// 23.243 us; speedup vs baseline: 2.4672x; 2.4672x over previous
//
#include <hip/hip_runtime.h>
#include <math.h>

#define B_ 4
#define T_ 512
#define D_ 2048
#define H_ 1024
#define E_ 2

#define LD4(p) (*reinterpret_cast<const float4*>(p))

// Lessons (measured, this session):
//  R2: __threadfence => buffer_wbl2/inv cache maintenance, +38us. Never.
//  R4: spinning on an RMW'd line => ownership ping-pong, ~20us/barrier. Never.
//  R5: 512 same-line fetch_adds serialize (~15ns each), +7us. Never.
//  R6: even polite store-array grid barriers cost ~17us on gfx950. => no fusion;
//      the 4-node graph (this file) is the winning structure.

__device__ __forceinline__ float waveReduceSum(float v) {
    #pragma unroll
    for (int o = 32; o > 0; o >>= 1) v += __shfl_down(v, o, 64);
    return v;
}

// N1: w2s[row] = sum_d W2[row,d], row = e*H+h. 2 rows per wave -> 16 float4
// in flight per wave, 256 blocks (1 per CU).
__global__ __launch_bounds__(256) void k_w2sum(const float* __restrict__ W2,
                                               float* __restrict__ w2s) {
    int gw   = (blockIdx.x * 256 + threadIdx.x) >> 6;   // 0..1023
    int lane = threadIdx.x & 63;
    const float* p0 = W2 + (size_t)(2 * gw) * D_;
    const float* p1 = p0 + D_;
    float a0 = 0.f, a1 = 0.f;
    #pragma unroll
    for (int k = 0; k < D_ / 256; ++k) {                // 8 float4 per lane per row
        float4 u = LD4(p0 + (lane + k * 64) * 4);
        float4 w = LD4(p1 + (lane + k * 64) * 4);
        a0 += (u.x + u.y) + (u.z + u.w);
        a1 += (w.x + w.y) + (w.z + w.w);
    }
    #pragma unroll
    for (int o = 32; o > 0; o >>= 1) {
        a0 += __shfl_down(a0, o, 64);
        a1 += __shfl_down(a1, o, 64);
    }
    if (lane == 0) {
        w2s[2 * gw]     = a0;
        w2s[2 * gw + 1] = a1;
    }
}

// N2: v[e,d] = sum_h W1[e,d,h]*w2s[e,h]. 2 rows per wave (rows 2gw,2gw+1 share
// the expert since the pair never straddles the 2048 boundary) -> 12 float4 in
// flight. Blocks 512/513 compute c[e] = sum_h b1[e,h]*w2s[e,h] + sum_d b2[e,d].
__global__ __launch_bounds__(256) void k_vred(const float* __restrict__ W1,
                                              const float* __restrict__ w2s,
                                              const float* __restrict__ b1,
                                              const float* __restrict__ b2,
                                              float* __restrict__ v,
                                              float* __restrict__ c) {
    if (blockIdx.x >= 512) {
        __shared__ float lds[4];
        int e = blockIdx.x - 512;
        float acc = 0.f;
        for (int i = threadIdx.x; i < H_; i += 256) acc += b1[e * H_ + i] * w2s[e * H_ + i];
        for (int i = threadIdx.x; i < D_; i += 256) acc += b2[e * D_ + i];
        acc = waveReduceSum(acc);
        if ((threadIdx.x & 63) == 0) lds[threadIdx.x >> 6] = acc;
        __syncthreads();
        if (threadIdx.x == 0) c[e] = lds[0] + lds[1] + lds[2] + lds[3];
        return;
    }
    int gw   = (blockIdx.x * 256 + threadIdx.x) >> 6;   // 0..2047
    int lane = threadIdx.x & 63;
    int row0 = 2 * gw;                                  // 0..4094 (even)
    int e    = row0 >> 11;                              // row / D_
    const float* p0 = W1 + (size_t)row0 * H_;
    const float* p1 = p0 + H_;
    const float* w  = w2s + e * H_;
    float a0 = 0.f, a1 = 0.f;
    #pragma unroll
    for (int k = 0; k < H_ / 256; ++k) {                // 4 float4 per lane per row
        float4 wa = LD4(w  + (lane + k * 64) * 4);
        float4 u  = LD4(p0 + (lane + k * 64) * 4);
        float4 t  = LD4(p1 + (lane + k * 64) * 4);
        a0 += u.x * wa.x + u.y * wa.y + u.z * wa.z + u.w * wa.w;
        a1 += t.x * wa.x + t.y * wa.y + t.z * wa.z + t.w * wa.w;
    }
    #pragma unroll
    for (int o = 32; o > 0; o >>= 1) {
        a0 += __shfl_down(a0, o, 64);
        a1 += __shfl_down(a1, o, 64);
    }
    if (lane == 0) {
        v[row0]     = a0;
        v[row0 + 1] = a1;
    }
}

// N3: one wave per token: gate logits + both expert dots in one x pass,
// s[bt] = gate * (dot[idx] + c[idx]).  No fences, no atomics.
__global__ __launch_bounds__(256) void k_token(const float* __restrict__ x,
                                               const float* __restrict__ Wg,
                                               const float* __restrict__ v,
                                               const float* __restrict__ c,
                                               float* __restrict__ s) {
    int lane = threadIdx.x & 63;
    int bt   = (blockIdx.x * 256 + threadIdx.x) >> 6;   // 0..2047
    const float* xp = x + (size_t)bt * D_;
    float g0 = 0.f, g1 = 0.f, d0 = 0.f, d1 = 0.f;
    #pragma unroll
    for (int k = 0; k < D_ / 256; ++k) {                // 8 iterations
        int i = (lane + k * 64) * 4;
        float4 xv = LD4(xp + i);
        float4 v0 = LD4(v + i);
        float4 v1 = LD4(v + D_ + i);
        float4 wa = LD4(Wg + 2 * i);                    // Wg[d=i..i+1, e=0..1]
        float4 wb = LD4(Wg + 2 * i + 4);
        g0 += xv.x * wa.x + xv.y * wa.z + xv.z * wb.x + xv.w * wb.z;
        g1 += xv.x * wa.y + xv.y * wa.w + xv.z * wb.y + xv.w * wb.w;
        d0 += xv.x * v0.x + xv.y * v0.y + xv.z * v0.z + xv.w * v0.w;
        d1 += xv.x * v1.x + xv.y * v1.y + xv.z * v1.z + xv.w * v1.w;
    }
    #pragma unroll
    for (int o = 32; o > 0; o >>= 1) {
        g0 += __shfl_down(g0, o, 64);
        g1 += __shfl_down(g1, o, 64);
        d0 += __shfl_down(d0, o, 64);
        d1 += __shfl_down(d1, o, 64);
    }
    if (lane == 0) {
        int e = (g1 > g0) ? 1 : 0;                      // argmax, first index on tie
        float m  = fmaxf(g0, g1);
        float p0 = expf(g0 - m), p1 = expf(g1 - m);
        float gate = ((e == 0) ? p0 : p1) / (p0 + p1);
        float dot  = (e == 0) ? d0 : d1;
        s[bt] = gate * (dot + c[e]);
    }
}

// N4: out[b,t] = s[b,t] - max_t - log(sum_t exp(s - max_t)). One block per b.
__global__ void k_lsm(const float* __restrict__ s, float* __restrict__ out) {
    __shared__ float lds[8];
    int b = blockIdx.x;
    int t = threadIdx.x;                        // 512 threads, 8 waves
    int lane = t & 63, wid = t >> 6;
    float val = s[b * T_ + t];

    float m = val;
    #pragma unroll
    for (int o = 1; o < 64; o <<= 1) m = fmaxf(m, __shfl_xor(m, o, 64));
    if (lane == 0) lds[wid] = m;
    __syncthreads();
    m = lds[0];
    #pragma unroll
    for (int w = 1; w < 8; ++w) m = fmaxf(m, lds[w]);
    __syncthreads();

    float ex = expf(val - m);
    float sum = ex;
    #pragma unroll
    for (int o = 1; o < 64; o <<= 1) sum += __shfl_xor(sum, o, 64);
    if (lane == 0) lds[wid] = sum;
    __syncthreads();
    sum = 0.f;
    #pragma unroll
    for (int w = 0; w < 8; ++w) sum += lds[w];

    out[b * T_ + t] = val - m - logf(sum);
}

extern "C" void kernel_launch(void* const* d_in, const int* in_sizes, int n_in,
                              void* d_out, int out_size, void* d_ws, size_t ws_size,
                              hipStream_t stream) {
    (void)in_sizes; (void)n_in; (void)out_size; (void)ws_size;
    const float* x  = (const float*)d_in[0];
    const float* Wg = (const float*)d_in[1];
    const float* W1 = (const float*)d_in[2];
    const float* b1 = (const float*)d_in[3];
    const float* W2 = (const float*)d_in[4];
    const float* b2 = (const float*)d_in[5];
    float* out = (float*)d_out;

    float* ws  = (float*)d_ws;
    float* w2s = ws;                    // [E,H]  2048 floats
    float* v   = ws + 2048;             // [E,D]  4096 floats
    float* c   = ws + 6144;             // [E]    2 floats
    float* s   = ws + 6160;             // [B,T]  2048 floats, 16B-aligned

    k_w2sum<<<256, 256, 0, stream>>>(W2, w2s);
    k_vred <<<514, 256, 0, stream>>>(W1, w2s, b1, b2, v, c);
    k_token<<<512, 256, 0, stream>>>(x, Wg, v, c, s);
    k_lsm  <<<B_,  512, 0, stream>>>(s, out);
}